// Round 1
// baseline (217.560 us; speedup 1.0000x reference)
//
#include <hip/hip_runtime.h>

// out[s,b,d] = x[s,b,d] + (2047.5 - s), shape (4096, 4, 2048) fp32.
// Pure streaming, zero reuse: 268 MB total traffic, floor ~40 us @ 6.7 TB/s
// (harness fill dispatches measured 6.7 TB/s on this box).
// 4 float4s per thread, stride-256 interleave (perfect coalescing),
// nontemporal hints to avoid cache-allocate on a zero-reuse stream.
// Use clang ext_vector_type: __builtin_nontemporal_* rejects HIP_vector_type.
// B*D = 8192 floats per s-row = 2048 float4s => s = i4 >> 11.
//
// R0: resubmitted unchanged — previous round was an infra failure (no
// counters). Need the per-dispatch dur_us + FETCH/WRITE to decide whether
// the 217 us from the prior session is kernel time (then attack NT-store
// path / launch shape) or harness accounting (then this is the roofline).

typedef float fvec4 __attribute__((ext_vector_type(4)));

__global__ __launch_bounds__(256) void rpe_kernel(const fvec4* __restrict__ x,
                                                  fvec4* __restrict__ out) {
    int base = blockIdx.x * 1024 + threadIdx.x;

    fvec4 v[4];
    int idx[4];
    #pragma unroll
    for (int k = 0; k < 4; ++k) {
        idx[k] = base + k * 256;
        v[k] = __builtin_nontemporal_load(&x[idx[k]]);
    }
    #pragma unroll
    for (int k = 0; k < 4; ++k) {
        float bias = 2047.5f - (float)(idx[k] >> 11);
        v[k] += bias;   // ext_vector: scalar broadcast add
        __builtin_nontemporal_store(v[k], &out[idx[k]]);
    }
}

extern "C" void kernel_launch(void* const* d_in, const int* in_sizes, int n_in,
                              void* d_out, int out_size, void* d_ws, size_t ws_size,
                              hipStream_t stream) {
    const fvec4* x = (const fvec4*)d_in[0];
    fvec4* out = (fvec4*)d_out;
    int n4 = in_sizes[0] / 4;                 // 8,388,608, divisible by 1024
    int blocks = n4 / 1024;                   // 8192 blocks x 256 threads x 4 float4
    rpe_kernel<<<blocks, 256, 0, stream>>>(x, out);
}